// Round 16
// baseline (367.135 us; speedup 1.0000x reference)
//
#include <hip/hip_runtime.h>
#include <math.h>

#define NB 32768   // batch
// D=256, N=4, OUT=512, H=4, DH=64

typedef unsigned short u16;
typedef __attribute__((ext_vector_type(4))) float f32x4;
typedef __attribute__((ext_vector_type(8))) short bf16x8;

__device__ __forceinline__ float bf2f(u16 u){ return __uint_as_float(((unsigned int)u)<<16); }
__device__ __forceinline__ u16 f2bf(float f){
    unsigned int x = __float_as_uint(f);
    x += 0x7fffu + ((x>>16)&1u);   // round-to-nearest-even
    return (u16)(x>>16);
}
// gelu exact-erf via A&S 7.1.26 (|eps|<=1.5e-7), branchless: rcp + exp + 5 fma
__device__ __forceinline__ float gelu_f(float x){
    float z = fabsf(x) * 0.70710678118654752f;
    float t = __builtin_amdgcn_rcpf(1.0f + 0.3275911f*z);
    float p = t*(0.254829592f + t*(-0.284496736f + t*(1.421413741f + t*(-1.453152027f + t*1.061405429f))));
    float e = __expf(-z*z);
    float erf_abs = 1.0f - p*e;
    float erfv = copysignf(erf_abs, x);
    return 0.5f*x*(1.0f + erfv);
}

__device__ __forceinline__ void gload16(const void* g, void* l){
    __builtin_amdgcn_global_load_lds(
        (const __attribute__((address_space(1))) unsigned int*)g,
        (__attribute__((address_space(3))) unsigned int*)l, 16, 0, 0);
}

// ---------------- prep (scale w0..w3 by softmax(tfw)) + all weight fp32->bf16 conversions ----------------
__global__ __launch_bounds__(256) void prepconv_kernel(
    const float* __restrict__ w0, const float* __restrict__ w1,
    const float* __restrict__ w2, const float* __restrict__ w3,
    const float* __restrict__ tfw, u16* __restrict__ wcat,
    const float* __restrict__ ipw_s, u16* __restrict__ ipw_d,
    const float* __restrict__ op_s,  u16* __restrict__ op_d,
    const float* __restrict__ f1_s,  u16* __restrict__ f1_d,
    const float* __restrict__ f2_s,  u16* __restrict__ f2_d,
    const float* __restrict__ a1_s,  u16* __restrict__ a1_d)
{
    const int blk = blockIdx.x, tid = threadIdx.x;
    if (blk < 8192){
        float t0=tfw[0], t1=tfw[1], t2=tfw[2], t3=tfw[3];
        float m = fmaxf(fmaxf(t0,t1), fmaxf(t2,t3));
        float e0=expf(t0-m), e1=expf(t1-m), e2=expf(t2-m), e3=expf(t3-m);
        float inv = 1.0f/(e0+e1+e2+e3);
        float s0=e0*inv, s1=e1*inv, s2=e2*inv, s3=e3*inv;

        int idx = blk*256 + tid;
        int b  = idx >> 6;
        int d4 = (idx & 63) << 2;
        size_t src = (size_t)b*256 + d4;
        float4 a0 = *reinterpret_cast<const float4*>(w0 + src);
        float4 a1 = *reinterpret_cast<const float4*>(w1 + src);
        float4 a2 = *reinterpret_cast<const float4*>(w2 + src);
        float4 a3 = *reinterpret_cast<const float4*>(w3 + src);
        size_t dst = (size_t)b*1024 + d4;
        ushort4 o;
        o.x=f2bf(a0.x*s0); o.y=f2bf(a0.y*s0); o.z=f2bf(a0.z*s0); o.w=f2bf(a0.w*s0);
        *reinterpret_cast<ushort4*>(wcat + dst) = o;
        o.x=f2bf(a1.x*s1); o.y=f2bf(a1.y*s1); o.z=f2bf(a1.z*s1); o.w=f2bf(a1.w*s1);
        *reinterpret_cast<ushort4*>(wcat + dst + 256) = o;
        o.x=f2bf(a2.x*s2); o.y=f2bf(a2.y*s2); o.z=f2bf(a2.z*s2); o.w=f2bf(a2.w*s2);
        *reinterpret_cast<ushort4*>(wcat + dst + 512) = o;
        o.x=f2bf(a3.x*s3); o.y=f2bf(a3.y*s3); o.z=f2bf(a3.z*s3); o.w=f2bf(a3.w*s3);
        *reinterpret_cast<ushort4*>(wcat + dst + 768) = o;
    } else {
        int i = (blk - 8192)*256 + tid;   // float4 index across all weights
        const float* s; u16* d; int off;
        if      (i < 49152)  { s=ipw_s; d=ipw_d; off=i; }
        else if (i < 65536)  { s=op_s;  d=op_d;  off=i-49152; }
        else if (i < 327680) { s=f1_s;  d=f1_d;  off=i-65536; }
        else if (i < 458752) { s=f2_s;  d=f2_d;  off=i-327680; }
        else                 { s=a1_s;  d=a1_d;  off=i-458752; }
        float4 v = reinterpret_cast<const float4*>(s)[off];
        ushort4 o; o.x=f2bf(v.x); o.y=f2bf(v.y); o.z=f2bf(v.z); o.w=f2bf(v.w);
        reinterpret_cast<ushort4*>(d)[off] = o;
    }
}

// ---------------- 128x128 MFMA GEMM. ACT: 1 gelu, 2 gelu + fused a2 row-dot ----------------
template<int ACT>
__global__ __launch_bounds__(256) void mgemm_kernel(
    const u16* __restrict__ A, int lda,
    const u16* __restrict__ W, int ldw,
    const float* __restrict__ bias,
    u16* __restrict__ C, int ldc, int K,
    const float* __restrict__ a2w, const float* __restrict__ a2b, float* __restrict__ aln)
{
    __shared__ __align__(16) u16 sA[4096];   // [128][32]
    __shared__ __align__(16) u16 sB[4096];   // [128][32]

    const int tid  = threadIdx.x;
    const int lane = tid & 63;
    const int wid  = tid >> 6;
    const int wr   = wid >> 1, wc = wid & 1;
    const int row0 = blockIdx.x << 7, col0 = blockIdx.y << 7;

    const int e0 = tid << 3,          r0s = e0 >> 5, c0s = e0 & 31;
    const int e1 = (256 + tid) << 3,  r1s = e1 >> 5, c1s = e1 & 31;
    const u16* gA0 = A + (size_t)(row0 + r0s)*lda + c0s;
    const u16* gA1 = A + (size_t)(row0 + r1s)*lda + c1s;
    const u16* gB0 = W + (size_t)(col0 + r0s)*ldw + c0s;
    const u16* gB1 = W + (size_t)(col0 + r1s)*ldw + c1s;
    u16* lA0 = sA + (wid << 9);
    u16* lA1 = sA + 2048 + (wid << 9);
    u16* lB0 = sB + (wid << 9);
    u16* lB1 = sB + 2048 + (wid << 9);

    const int la  = lane & 15;
    const int lk  = (lane >> 4) << 3;
    const int hi4 = (lane >> 4) << 2;
    const u16* rA = sA + (((wr << 6) + la) << 5) + lk;
    const u16* rB = sB + (((wc << 6) + la) << 5) + lk;

    f32x4 acc[4][4];
    {
        f32x4 binit[4];
        #pragma unroll
        for (int n=0;n<4;n++){
            float4 b4 = *reinterpret_cast<const float4*>(bias + col0 + (wc<<6) + (n<<4) + hi4);
            binit[n] = (f32x4){b4.x, b4.y, b4.z, b4.w};
        }
        #pragma unroll
        for (int m=0;m<4;m++)
            #pragma unroll
            for (int n=0;n<4;n++) acc[m][n] = binit[n];
    }

    for (int k0 = 0; k0 < K; k0 += 32){
        gload16(gA0 + k0, lA0);
        gload16(gA1 + k0, lA1);
        gload16(gB0 + k0, lB0);
        gload16(gB1 + k0, lB1);
        __syncthreads();
        bf16x8 af[4], bf[4];
        #pragma unroll
        for (int m=0;m<4;m++) af[m] = *reinterpret_cast<const bf16x8*>(rA + (m << 9));
        #pragma unroll
        for (int n=0;n<4;n++) bf[n] = *reinterpret_cast<const bf16x8*>(rB + (n << 9));
        #pragma unroll
        for (int m=0;m<4;m++)
            #pragma unroll
            for (int n=0;n<4;n++)
                acc[m][n] = __builtin_amdgcn_mfma_f32_16x16x32_bf16(bf[n], af[m], acc[m][n], 0, 0, 0);
        __syncthreads();
    }

    if (ACT == 2){
        // fused: alignment[row] = sigmoid( sum_col gelu(val)*a2w[col] + a2b )
        float w4[4][4];
        #pragma unroll
        for (int n=0;n<4;n++){
            float4 t4 = *reinterpret_cast<const float4*>(a2w + (wc<<6) + (n<<4) + hi4);
            w4[n][0]=t4.x; w4[n][1]=t4.y; w4[n][2]=t4.z; w4[n][3]=t4.w;
        }
        float* red = reinterpret_cast<float*>(sA);   // [128 rows][8 slots], 4KB
        #pragma unroll
        for (int m=0;m<4;m++){
            float p = 0.f;
            #pragma unroll
            for (int n=0;n<4;n++){
                f32x4 v = acc[m][n];
                p += gelu_f(v[0])*w4[n][0] + gelu_f(v[1])*w4[n][1]
                   + gelu_f(v[2])*w4[n][2] + gelu_f(v[3])*w4[n][3];
            }
            red[(((wr<<6) + (m<<4) + la) << 3) + (wc<<2) + (lane>>4)] = p;
        }
        __syncthreads();
        if (tid < 128){
            float s = 0.f;
            #pragma unroll
            for (int k2=0;k2<8;k2++) s += red[(tid<<3)+k2];
            aln[row0 + tid] = 1.0f/(1.0f + __expf(-(s + a2b[0])));
        }
        return;
    }

    #pragma unroll
    for (int m=0;m<4;m++){
        const int grow = row0 + (wr << 6) + (m << 4) + la;
        u16* crow = C + (size_t)grow*ldc + col0 + (wc << 6) + hi4;
        #pragma unroll
        for (int n=0;n<4;n++){
            f32x4 v = acc[m][n];
            float x0=v[0], x1=v[1], x2=v[2], x3=v[3];
            if (ACT == 1){ x0=gelu_f(x0); x1=gelu_f(x1); x2=gelu_f(x2); x3=gelu_f(x3); }
            ushort4 o; o.x=f2bf(x0); o.y=f2bf(x1); o.z=f2bf(x2); o.w=f2bf(x3);
            *reinterpret_cast<ushort4*>(crow + (n << 4)) = o;
        }
    }
}

// ---------------- 256x256 MFMA GEMM, BK=64, 2-buf, 4 phases/tile, no setprio (r14 engine) ----------------
template<int ACT>
__global__ __launch_bounds__(512) void gemm256p_kernel(
    const u16* __restrict__ A, int lda,
    const u16* __restrict__ W, int ldw,
    const float* __restrict__ bias,
    u16* __restrict__ C, int ldc, int K)
{
    __shared__ __align__(16) u16 sT[65536];   // 128 KiB

    const int tid  = threadIdx.x;
    const int lane = tid & 63;
    const int wid  = tid >> 6;            // 0..7
    const int wr   = wid >> 2;            // 0..1
    const int wc   = wid & 3;             // 0..3
    const int row0 = blockIdx.x << 8, col0 = blockIdx.y << 8;

    const int la = lane & 15;
    const int hi = lane >> 4;

    f32x4 acc[8][4];
    {
        f32x4 binit[4];
        #pragma unroll
        for (int n=0;n<4;n++){
            float4 b4 = *reinterpret_cast<const float4*>(bias + col0 + (wc<<6) + (n<<4) + (hi<<2));
            binit[n] = (f32x4){b4.x, b4.y, b4.z, b4.w};
        }
        #pragma unroll
        for (int m=0;m<8;m++)
            #pragma unroll
            for (int n=0;n<4;n++) acc[m][n] = binit[n];
    }

    const int rs = (wid << 4) + (lane >> 3);
    const int cs = ((lane & 7) ^ ((lane >> 3) & 7)) << 3;
    const u16* gA0 = A + (size_t)(row0 + rs)*lda + cs;
    const u16* gA1 = gA0 + (size_t)128*lda;
    const u16* gB0 = W + (size_t)(col0 + rs)*ldw + cs;
    const u16* gB1 = gB0 + (size_t)128*ldw;
    const int ldsw = (wid << 4) * 64;

    const int cph0 = (hi ^ (la & 7)) << 3;
    const u16* rAbase = sT + ((wr << 7) + la)*64;
    const u16* rBbase = sT + 16384 + ((wc << 6) + la)*64;

    const int NT = K >> 6;

    gload16(gB0, sT + 16384 + ldsw);          gload16(gB0 + 8*(size_t)ldw, sT + 16384 + ldsw + 512);
    gload16(gB1, sT + 24576 + ldsw);          gload16(gB1 + 8*(size_t)ldw, sT + 24576 + ldsw + 512);
    gload16(gA0, sT + ldsw);                  gload16(gA0 + 8*(size_t)lda, sT + ldsw + 512);
    gload16(gA1, sT + 8192 + ldsw);           gload16(gA1 + 8*(size_t)lda, sT + 8192 + ldsw + 512);

#define STG(GP, LD, DOFF) \
        gload16(GP + kb, sT + bn + (DOFF) + ldsw); \
        gload16(GP + kb + 8*(size_t)(LD), sT + bn + (DOFF) + ldsw + 512);

#define DSRA(MH, CO) { \
        const u16* rA_ = rAbase + b + ((MH) << 12) + (CO); \
        af[0] = *reinterpret_cast<const bf16x8*>(rA_); \
        af[1] = *reinterpret_cast<const bf16x8*>(rA_ + 1024); \
        af[2] = *reinterpret_cast<const bf16x8*>(rA_ + 2048); \
        af[3] = *reinterpret_cast<const bf16x8*>(rA_ + 3072); }

#define DSRB(CO) { \
        const u16* rB_ = rBbase + b + (CO); \
        bf[0] = *reinterpret_cast<const bf16x8*>(rB_); \
        bf[1] = *reinterpret_cast<const bf16x8*>(rB_ + 1024); \
        bf[2] = *reinterpret_cast<const bf16x8*>(rB_ + 2048); \
        bf[3] = *reinterpret_cast<const bf16x8*>(rB_ + 3072); }

#define MFMA16(MB) { \
        _Pragma("unroll") \
        for (int m=0;m<4;m++){ \
            _Pragma("unroll") \
            for (int n=0;n<4;n++) \
                acc[(MB)+m][n] = __builtin_amdgcn_mfma_f32_16x16x32_bf16(bf[n], af[m], acc[(MB)+m][n], 0,0,0); \
        } }

    for (int t = 0; t < NT; ++t){
        const int b  = (t & 1) << 15;
        const int bn = b ^ 32768;
        const bool stg = (t + 1 < NT);
        const int kb = (t + 1) << 6;
        bf16x8 af[4], bf[4];
        const int co0 = cph0;
        const int co1 = cph0 ^ 32;

        asm volatile("s_waitcnt vmcnt(0)" ::: "memory");
        __builtin_amdgcn_s_barrier();
        __builtin_amdgcn_sched_barrier(0);
        DSRB(co0)
        DSRA(0, co0)
        if (stg){ STG(gB0, ldw, 16384) }
        MFMA16(0)
        DSRA(1, co0)
        if (stg){ STG(gB1, ldw, 24576) }
        __builtin_amdgcn_sched_barrier(0);
        __builtin_amdgcn_s_barrier();
        __builtin_amdgcn_sched_barrier(0);
        MFMA16(4)
        DSRB(co1)
        DSRA(0, co1)
        if (stg){ STG(gA0, lda, 0) }
        __builtin_amdgcn_sched_barrier(0);
        __builtin_amdgcn_s_barrier();
        __builtin_amdgcn_sched_barrier(0);
        MFMA16(0)
        DSRA(1, co1)
        if (stg){ STG(gA1, lda, 8192) }
        __builtin_amdgcn_sched_barrier(0);
        __builtin_amdgcn_s_barrier();
        __builtin_amdgcn_sched_barrier(0);
        MFMA16(4)
    }
#undef STG
#undef DSRA
#undef DSRB
#undef MFMA16

    #pragma unroll
    for (int m=0;m<8;m++){
        const int grow = row0 + (wr << 7) + (m << 4) + la;
        u16* crow = C + (size_t)grow*ldc + col0 + (wc << 6) + (hi << 2);
        #pragma unroll
        for (int n=0;n<4;n++){
            f32x4 v = acc[m][n];
            float x0=v[0], x1=v[1], x2=v[2], x3=v[3];
            if (ACT == 1){ x0=gelu_f(x0); x1=gelu_f(x1); x2=gelu_f(x2); x3=gelu_f(x3); }
            ushort4 o; o.x=f2bf(x0); o.y=f2bf(x1); o.z=f2bf(x2); o.w=f2bf(x3);
            *reinterpret_cast<ushort4*>(crow + (n << 4)) = o;
        }
    }
}

// ---------------- FUSED: q-proj + attention + out_proj + LN+FiLM -> entry (overwrites wcat[b][0]) ----------------
// Block = 16 samples, 256 threads (4 waves). Grid = 2048.
__global__ __launch_bounds__(256) void attnop_kernel(
    const u16* __restrict__ kv,
    u16* __restrict__ wcat,
    const u16* __restrict__ ipw, const float* __restrict__ ipb,   // q-part: rows 0..255, bias 0..255
    const u16* __restrict__ opw, const float* __restrict__ opb,
    const float* __restrict__ regime,
    const float* __restrict__ sgw, const float* __restrict__ sgb,
    const float* __restrict__ sbw, const float* __restrict__ sbb,
    const float* __restrict__ g1, const float* __restrict__ b1)
{
    __shared__ __align__(16) u16 sKV[32768];      // 16 x 2048 (k|v per n); later sAO = f32[16][264]
    __shared__ __align__(16) u16 sQC[16*264];     // query -> q -> ctx, row stride 264
    __shared__ float sAT[256];                    // attn weights (s*16 + h*4 + n)

    const int t  = threadIdx.x;
    const int b0 = blockIdx.x << 4;

    // ---- load query (wcat row 0) + kv ----
    {
        const int row = t >> 4, u = t & 15;
        const u16* qsrc = wcat + (size_t)(b0 + row)*1024 + (u << 4);
        *reinterpret_cast<bf16x8*>(sQC + row*264 + (u<<4))     = *reinterpret_cast<const bf16x8*>(qsrc);
        *reinterpret_cast<bf16x8*>(sQC + row*264 + (u<<4) + 8) = *reinterpret_cast<const bf16x8*>(qsrc + 8);
        const u16* kvsrc = kv + (size_t)b0*2048;
        #pragma unroll
        for (int j=0;j<16;j++){
            const int off = (t<<3) + j*2048;
            *reinterpret_cast<bf16x8*>(sKV + off) = *reinterpret_cast<const bf16x8*>(kvsrc + off);
        }
    }
    __syncthreads();

    // ---- q = query @ wq^T + bq (MFMA; per-wave 16 rows x 64 cols), result kept in regs ----
    const int lane = t & 63, wid = t >> 6;
    const int la = lane & 15, hi = lane >> 4;
    f32x4 qacc[4];
    {
        #pragma unroll
        for (int n=0;n<4;n++){
            float4 b4 = *reinterpret_cast<const float4*>(ipb + (wid<<6) + (n<<4) + (hi<<2));
            qacc[n] = (f32x4){b4.x, b4.y, b4.z, b4.w};
        }
        #pragma unroll
        for (int kk=0; kk<8; ++kk){
            bf16x8 af = *reinterpret_cast<const bf16x8*>(sQC + la*264 + (kk<<5) + (hi<<3));
            #pragma unroll
            for (int n=0;n<4;n++){
                bf16x8 wf = *reinterpret_cast<const bf16x8*>(
                    ipw + (size_t)((wid<<6) + (n<<4) + la)*256 + (kk<<5) + (hi<<3));
                qacc[n] = __builtin_amdgcn_mfma_f32_16x16x32_bf16(wf, af, qacc[n], 0, 0, 0);
            }
        }
    }
    __syncthreads();   // all query reads done -> safe to overwrite sQC with q
    {
        #pragma unroll
        for (int n=0;n<4;n++){
            ushort4 o;
            o.x = f2bf(qacc[n][0]); o.y = f2bf(qacc[n][1]);
            o.z = f2bf(qacc[n][2]); o.w = f2bf(qacc[n][3]);
            *reinterpret_cast<ushort4*>(sQC + la*264 + (wid<<6) + (n<<4) + (hi<<2)) = o;
        }
    }
    __syncthreads();

    // ---- scores + softmax: thread t = (s, h, n); shfl over n ----
    {
        const int s = t >> 4, h = (t >> 2) & 3, n = t & 3;
        float sc = 0.f;
        const u16* qp = sQC + s*264 + h*64;
        const u16* kp = sKV + s*2048 + n*512 + h*64;
        #pragma unroll
        for (int dh=0; dh<64; ++dh) sc += bf2f(qp[dh]) * bf2f(kp[dh]);
        sc *= 0.125f;
        float m = fmaxf(sc, __shfl_xor(sc, 1)); m = fmaxf(m, __shfl_xor(m, 2));
        float e = __expf(sc - m);
        float sum = e + __shfl_xor(e, 1); sum += __shfl_xor(sum, 2);
        sAT[t] = e / sum;
    }
    __syncthreads();

    // ---- ctx[s][d] -> sQC ----
    {
        const int s = t >> 4, u = t & 15;
        #pragma unroll
        for (int j=0;j<16;j++){
            const int d = (u << 4) + j;
            const int h = d >> 6;
            const float* a = sAT + s*16 + (h<<2);
            const u16* vp = sKV + s*2048 + 256 + d;
            float c = a[0]*bf2f(vp[0]) + a[1]*bf2f(vp[512]) + a[2]*bf2f(vp[1024]) + a[3]*bf2f(vp[1536]);
            sQC[s*264 + d] = f2bf(c);
        }
    }
    __syncthreads();   // ctx visible; kv dead

    // ---- ao = ctx @ opw^T + opb via MFMA ----
    float* sAO = reinterpret_cast<float*>(sKV);   // f32 [16][264]
    {
        f32x4 acc[4];
        #pragma unroll
        for (int n=0;n<4;n++){
            float4 b4 = *reinterpret_cast<const float4*>(opb + (wid<<6) + (n<<4) + (hi<<2));
            acc[n] = (f32x4){b4.x, b4.y, b4.z, b4.w};
        }
        #pragma unroll
        for (int ks=0; ks<8; ++ks){
            bf16x8 af = *reinterpret_cast<const bf16x8*>(sQC + la*264 + (ks<<5) + (hi<<3));
            #pragma unroll
            for (int n=0;n<4;n++){
                bf16x8 wf = *reinterpret_cast<const bf16x8*>(
                    opw + (size_t)((wid<<6) + (n<<4) + la)*256 + (ks<<5) + (hi<<3));
                acc[n] = __builtin_amdgcn_mfma_f32_16x16x32_bf16(wf, af, acc[n], 0, 0, 0);
            }
        }
        #pragma unroll
        for (int n=0;n<4;n++){
            float4 st = {acc[n][0], acc[n][1], acc[n][2], acc[n][3]};
            *reinterpret_cast<float4*>(sAO + la*264 + (wid<<6) + (n<<4) + (hi<<2)) = st;
        }
    }
    __syncthreads();

    // ---- entry = FiLM(LN(query + ao)) -> wcat row 0 ----
    {
        const int s = t >> 4, u = t & 15;
        u16* qrow = wcat + (size_t)(b0 + s)*1024;
        float xv[16], sum = 0.f, sq = 0.f;
        #pragma unroll
        for (int j=0;j<16;j++){
            const int d = u + (j << 4);
            float x = sAO[s*264 + d] + bf2f(qrow[d]);
            xv[j] = x; sum += x; sq += x*x;
        }
        #pragma unroll
        for (int o=1;o<16;o<<=1){ sum += __shfl_xor(sum, o); sq += __shfl_xor(sq, o); }
        float mu   = sum * (1.0f/256.0f);
        float var  = sq  * (1.0f/256.0f) - mu*mu;
        float rstd = rsqrtf(var + 1e-5f);
        const float r0 = regime[(b0+s)*4+0], r1 = regime[(b0+s)*4+1];
        const float r2 = regime[(b0+s)*4+2], r3 = regime[(b0+s)*4+3];
        #pragma unroll
        for (int j=0;j<16;j++){
            const int d = u + (j << 4);
            float gam = r0*sgw[d*4+0] + r1*sgw[d*4+1] + r2*sgw[d*4+2] + r3*sgw[d*4+3] + sgb[d];
            float bet = r0*sbw[d*4+0] + r1*sbw[d*4+1] + r2*sbw[d*4+2] + r3*sbw[d*4+3] + sbb[d];
            float e = ((xv[j]-mu)*rstd*g1[d] + b1[d])*(1.0f+gam) + bet;
            qrow[d] = f2bf(e);
        }
    }
}

// ---------------- FUSED f2 GEMM (128 x 512, BK=32, r9 schedule) + LN2 -> f32 out ----------------
// 512 threads = 8 waves (2M x 4N): per-wave 64 rows x 128 cols = 4 Mfrag x 8 Nfrag.
// LDS per buf: A[128][32] @0, B[512][32] @4096 (elems); 2 bufs = 40960 elems. Overlay for LN: bf16[128][520].
// Swizzle (r9-verified): phys chunk = logical ^ ((row>>1)&3); inverse-permuted global source.
__global__ __launch_bounds__(512) void f2ln_kernel(
    const u16* __restrict__ A,            // hbuf [32768][1024]
    const u16* __restrict__ W,            // f2w  [512][1024]
    const float* __restrict__ bias,       // f2_b [512]
    const float* __restrict__ g, const float* __restrict__ bt,   // ln2
    float* __restrict__ out)              // [32768][512] f32
{
    __shared__ __align__(16) u16 sT[66560];   // max(2x20480 staging, 128x520 overlay) = 133120 B

    const int tid  = threadIdx.x;
    const int lane = tid & 63;
    const int wid  = tid >> 6;            // 0..7
    const int wr   = wid >> 2;            // 0..1 (rows)
    const int wc   = wid & 3;             // 0..3 (cols)
    const int row0 = blockIdx.x << 7;

    const int la = lane & 15;
    const int hi = lane >> 4;

    f32x4 acc[4][8];
    {
        #pragma unroll
        for (int n=0;n<8;n++){
            float4 b4 = *reinterpret_cast<const float4*>(bias + (wc<<7) + (n<<4) + (hi<<2));
            f32x4 bi = (f32x4){b4.x, b4.y, b4.z, b4.w};
            #pragma unroll
            for (int m=0;m<4;m++) acc[m][n] = bi;
        }
    }

    // staging: wave stages A rows [wid*16,+16) (1 gload) and B rows [wid*64,+64) (4 gloads)
    const int rsA = (wid << 4) + (lane >> 2);
    const int rsB = (wid << 6) + (lane >> 2);
    const int swA = ((lane & 3) ^ ((rsA >> 1) & 3)) << 3;
    const int swB = ((lane & 3) ^ ((rsB >> 1) & 3)) << 3;   // row+16 doesn't change ((row>>1)&3)... (16>>1)&3=0? (r+16)>>1 = r>>1 + 8 -> &3 same
    const u16* pA = A + (size_t)(row0 + rsA)*1024 + swA;
    const u16* pB = W + (size_t)rsB*1024 + swB;

    const int cph0 = (hi ^ ((la >> 1) & 3)) << 3;

    const int NT = 32;   // K=1024 / 32

    // prologue: tile 0 -> buf 0
    gload16(pA, sT + (wid<<9));
    #pragma unroll
    for (int j=0;j<4;j++) gload16(pB + (size_t)(j<<4)*1024, sT + 4096 + (wid<<11) + (j<<9));

    for (int t = 0; t < NT; ++t){
        const int b  = (t & 1) ? 20480 : 0;
        const int bn = b ? 0 : 20480;
        const int kb = (t + 1) << 5;

        asm volatile("s_waitcnt vmcnt(0)" ::: "memory");
        __builtin_amdgcn_s_barrier();
        __builtin_amdgcn_sched_barrier(0);

        if (t + 1 < NT){
            gload16(pA + kb, sT + bn + (wid<<9));
            #pragma unroll
            for (int j=0;j<4;j++) gload16(pB + (size_t)(j<<4)*1024 + kb, sT + bn + 4096 + (wid<<11) + (j<<9));
        }

        bf16x8 af[4], bf[8];
        #pragma unroll
        for (int m=0;m<4;m++){
            const int r = (wr<<6) + (m<<4) + la;
            af[m] = *reinterpret_cast<const bf16x8*>(sT + b + (r<<5) + cph0);
        }
        #pragma unroll
        for (int n=0;n<8;n++){
            const int r = (wc<<7) + (n<<4) + la;
            bf[n] = *reinterpret_cast<const bf16x8*>(sT + b + 4096 + (r<<5) + cph0);
        }
        #pragma unroll
        for (int m=0;m<4;m++)
            #pragma unroll
            for (int n=0;n<8;n++)
                acc[m][n] = __builtin_amdgcn_mfma_f32_16x16x32_bf16(bf[n], af[m], acc[m][n], 0, 0, 0);
    }

    // ---- epilogue: acc -> LDS bf16 [128][520], per-row LN, write f32 out ----
    __builtin_amdgcn_s_barrier();
    #pragma unroll
    for (int m=0;m<4;m++){
        const int r = (wr<<6) + (m<<4) + la;
        u16* rowp = sT + r*520 + (wc<<7) + (hi<<2);
        #pragma unroll
        for (int n=0;n<8;n++){
            ushort4 o;
            o.x = f2bf(acc[m][n][0]); o.y = f2bf(acc[m][n][1]);
            o.z = f2bf(acc[m][n][2]); o.w = f2bf(acc[m][n][3]);
            *reinterpret_cast<ushort4*>(rowp + (n<<4)) = o;
        }
    }
    __syncthreads();

    {
        const int r  = tid >> 2;        // 0..127
        const int q4 = tid & 3;         // quarter: cols q4*128..+127
        const u16* rowp = sT + r*520 + (q4<<7);
        float sum = 0.f, sq = 0.f;
        #pragma unroll
        for (int i=0;i<16;i++){
            bf16x8 v = *reinterpret_cast<const bf16x8*>(rowp + (i<<3));
            #pragma unroll
            for (int k=0;k<8;k++){ float x = bf2f((u16)v[k]); sum += x; sq += x*x; }
        }
        sum += __shfl_xor(sum, 1); sq += __shfl_xor(sq, 1);
        sum += __shfl_xor(sum, 2); sq += __shfl_xor(sq, 2);
        float mu   = sum * (1.0f/512.0f);
        float var  = sq  * (1.0f/512.0f) - mu*mu;
        float rstd = rsqrtf(var + 1e-5f);
        float* orow = out + (size_t)(row0 + r)*512 + (q4<<7);
        #pragma unroll
        for (int i=0;i<16;i++){
            bf16x8 v = *reinterpret_cast<const bf16x8*>(rowp + (i<<3));
            const int c0 = (q4<<7) + (i<<3);
            float4 o0, o1;
            o0.x = (bf2f((u16)v[0])-mu)*rstd*g[c0+0] + bt[c0+0];
            o0.y = (bf2f((u16)v[1])-mu)*rstd*g[c0+1] + bt[c0+1];
            o0.z = (bf2f((u16)v[2])-mu)*rstd*g[c0+2] + bt[c0+2];
            o0.w = (bf2f((u16)v[3])-mu)*rstd*g[c0+3] + bt[c0+3];
            o1.x = (bf2f((u16)v[4])-mu)*rstd*g[c0+4] + bt[c0+4];
            o1.y = (bf2f((u16)v[5])-mu)*rstd*g[c0+5] + bt[c0+5];
            o1.z = (bf2f((u16)v[6])-mu)*rstd*g[c0+6] + bt[c0+6];
            o1.w = (bf2f((u16)v[7])-mu)*rstd*g[c0+7] + bt[c0+7];
            *reinterpret_cast<float4*>(orow + (i<<3))     = o0;
            *reinterpret_cast<float4*>(orow + (i<<3) + 4) = o1;
        }
    }
}

extern "C" void kernel_launch(void* const* d_in, const int* in_sizes, int n_in,
                              void* d_out, int out_size, void* d_ws, size_t ws_size,
                              hipStream_t stream) {
    const float* w0   = (const float*)d_in[0];
    const float* w1   = (const float*)d_in[1];
    const float* w2   = (const float*)d_in[2];
    const float* w3   = (const float*)d_in[3];
    const float* regime = (const float*)d_in[4];
    const float* tfw  = (const float*)d_in[5];
    const float* in_proj_w = (const float*)d_in[6];
    const float* in_proj_b = (const float*)d_in[7];
    const float* out_proj_w = (const float*)d_in[8];
    const float* out_proj_b = (const float*)d_in[9];
    const float* ln1_g = (const float*)d_in[10];
    const float* ln1_b = (const float*)d_in[11];
    const float* sg_w = (const float*)d_in[12];
    const float* sg_b = (const float*)d_in[13];
    const float* sb_w = (const float*)d_in[14];
    const float* sb_b = (const float*)d_in[15];
    const float* f1_w = (const float*)d_in[16];
    const float* f1_b = (const float*)d_in[17];
    const float* f2_w = (const float*)d_in[18];
    const float* f2_b = (const float*)d_in[19];
    const float* ln2_g = (const float*)d_in[20];
    const float* ln2_b = (const float*)d_in[21];
    const float* a1_w = (const float*)d_in[22];
    const float* a1_b = (const float*)d_in[23];
    const float* a2_w = (const float*)d_in[24];
    const float* a2_b = (const float*)d_in[25];

    char* ws = (char*)d_ws;
    u16* wcat  = (u16*)(ws);
    u16* kvbuf = (u16*)(ws + 83886080ull);
    u16* hbuf  = kvbuf;
    u16* dummy = (u16*)(ws + 67108864ull);     // scratch (unused C for ACT=2)
    u16* wb    = (u16*)(ws + 218103808ull);
    u16* ipw = wb;                // 196608 elems
    u16* opw = wb + 196608;       // 65536
    u16* f1w = wb + 262144;       // 1048576
    u16* f2w = wb + 1310720;      // 524288
    u16* a1w = wb + 1835008;      // 131072

    float* out_fused = (float*)d_out;
    float* out_align = (float*)d_out + (size_t)NB*512;

    // 1. prep + all weight conversions
    prepconv_kernel<<<10112, 256, 0, stream>>>(w0,w1,w2,w3,tfw,wcat,
        in_proj_w,ipw, out_proj_w,opw, f1_w,f1w, f2_w,f2w, a1_w,a1w);
    // 2. kv = weighted @ [wk;wv]^T + b  (M = 4B rows, N = 512)
    gemm256p_kernel<0><<<dim3(512, 2), 512, 0, stream>>>(wcat, 256, ipw+65536, 256, in_proj_b+256, kvbuf, 512, 256);
    // 3. FUSED q-proj + attention + out_proj + LN+FiLM -> wcat entry rows
    attnop_kernel<<<2048, 256, 0, stream>>>(kvbuf, wcat, ipw, in_proj_b, opw, out_proj_b,
        regime, sg_w, sg_b, sb_w, sb_b, ln1_g, ln1_b);
    // 4. h = gelu(cat @ f1^T + b) -> hbuf
    gemm256p_kernel<1><<<dim3(128, 4), 512, 0, stream>>>(wcat, 1024, f1w, 1024, f1_b, hbuf, 1024, 1024);
    // 5. FUSED t1 = h @ f2^T + b, fused = LN(t1) -> out
    f2ln_kernel<<<256, 512, 0, stream>>>(hbuf, f2w, f2_b, ln2_g, ln2_b, out_fused);
    // 6. alignment = sigmoid(gelu(cat @ a1^T + b) @ a2^T + b)
    mgemm_kernel<2><<<dim3(256, 1), 256, 0, stream>>>(wcat, 1024, a1w, 1024, a1_b, dummy, 128, 1024, a2_w, a2_b, out_align);
}

// Round 17
// 349.431 us; speedup vs baseline: 1.0507x; 1.0507x over previous
//
#include <hip/hip_runtime.h>
#include <math.h>

#define NB 32768   // batch
// D=256, N=4, OUT=512, H=4, DH=64

typedef unsigned short u16;
typedef __attribute__((ext_vector_type(4))) float f32x4;
typedef __attribute__((ext_vector_type(8))) short bf16x8;

__device__ __forceinline__ float bf2f(u16 u){ return __uint_as_float(((unsigned int)u)<<16); }
__device__ __forceinline__ u16 f2bf(float f){
    unsigned int x = __float_as_uint(f);
    x += 0x7fffu + ((x>>16)&1u);   // round-to-nearest-even
    return (u16)(x>>16);
}
// gelu exact-erf via A&S 7.1.26 (|eps|<=1.5e-7), branchless: rcp + exp + 5 fma
__device__ __forceinline__ float gelu_f(float x){
    float z = fabsf(x) * 0.70710678118654752f;
    float t = __builtin_amdgcn_rcpf(1.0f + 0.3275911f*z);
    float p = t*(0.254829592f + t*(-0.284496736f + t*(1.421413741f + t*(-1.453152027f + t*1.061405429f))));
    float e = __expf(-z*z);
    float erf_abs = 1.0f - p*e;
    float erfv = copysignf(erf_abs, x);
    return 0.5f*x*(1.0f + erfv);
}

__device__ __forceinline__ void gload16(const void* g, void* l){
    __builtin_amdgcn_global_load_lds(
        (const __attribute__((address_space(1))) unsigned int*)g,
        (__attribute__((address_space(3))) unsigned int*)l, 16, 0, 0);
}

// ---------------- prep (scale w0..w3 by softmax(tfw)) + all weight fp32->bf16 conversions ----------------
__global__ __launch_bounds__(256) void prepconv_kernel(
    const float* __restrict__ w0, const float* __restrict__ w1,
    const float* __restrict__ w2, const float* __restrict__ w3,
    const float* __restrict__ tfw, u16* __restrict__ wcat,
    const float* __restrict__ ipw_s, u16* __restrict__ ipw_d,
    const float* __restrict__ op_s,  u16* __restrict__ op_d,
    const float* __restrict__ f1_s,  u16* __restrict__ f1_d,
    const float* __restrict__ f2_s,  u16* __restrict__ f2_d,
    const float* __restrict__ a1_s,  u16* __restrict__ a1_d)
{
    const int blk = blockIdx.x, tid = threadIdx.x;
    if (blk < 8192){
        float t0=tfw[0], t1=tfw[1], t2=tfw[2], t3=tfw[3];
        float m = fmaxf(fmaxf(t0,t1), fmaxf(t2,t3));
        float e0=expf(t0-m), e1=expf(t1-m), e2=expf(t2-m), e3=expf(t3-m);
        float inv = 1.0f/(e0+e1+e2+e3);
        float s0=e0*inv, s1=e1*inv, s2=e2*inv, s3=e3*inv;

        int idx = blk*256 + tid;
        int b  = idx >> 6;
        int d4 = (idx & 63) << 2;
        size_t src = (size_t)b*256 + d4;
        float4 a0 = *reinterpret_cast<const float4*>(w0 + src);
        float4 a1 = *reinterpret_cast<const float4*>(w1 + src);
        float4 a2 = *reinterpret_cast<const float4*>(w2 + src);
        float4 a3 = *reinterpret_cast<const float4*>(w3 + src);
        size_t dst = (size_t)b*1024 + d4;
        ushort4 o;
        o.x=f2bf(a0.x*s0); o.y=f2bf(a0.y*s0); o.z=f2bf(a0.z*s0); o.w=f2bf(a0.w*s0);
        *reinterpret_cast<ushort4*>(wcat + dst) = o;
        o.x=f2bf(a1.x*s1); o.y=f2bf(a1.y*s1); o.z=f2bf(a1.z*s1); o.w=f2bf(a1.w*s1);
        *reinterpret_cast<ushort4*>(wcat + dst + 256) = o;
        o.x=f2bf(a2.x*s2); o.y=f2bf(a2.y*s2); o.z=f2bf(a2.z*s2); o.w=f2bf(a2.w*s2);
        *reinterpret_cast<ushort4*>(wcat + dst + 512) = o;
        o.x=f2bf(a3.x*s3); o.y=f2bf(a3.y*s3); o.z=f2bf(a3.z*s3); o.w=f2bf(a3.w*s3);
        *reinterpret_cast<ushort4*>(wcat + dst + 768) = o;
    } else {
        int i = (blk - 8192)*256 + tid;   // float4 index across all weights
        const float* s; u16* d; int off;
        if      (i < 49152)  { s=ipw_s; d=ipw_d; off=i; }
        else if (i < 65536)  { s=op_s;  d=op_d;  off=i-49152; }
        else if (i < 327680) { s=f1_s;  d=f1_d;  off=i-65536; }
        else if (i < 458752) { s=f2_s;  d=f2_d;  off=i-327680; }
        else                 { s=a1_s;  d=a1_d;  off=i-458752; }
        float4 v = reinterpret_cast<const float4*>(s)[off];
        ushort4 o; o.x=f2bf(v.x); o.y=f2bf(v.y); o.z=f2bf(v.z); o.w=f2bf(v.w);
        reinterpret_cast<ushort4*>(d)[off] = o;
    }
}

// ---------------- 128x128 MFMA GEMM. ACT: 0 none, 1 gelu, 2 gelu + fused a2 row-dot ----------------
template<int ACT>
__global__ __launch_bounds__(256) void mgemm_kernel(
    const u16* __restrict__ A, int lda,
    const u16* __restrict__ W, int ldw,
    const float* __restrict__ bias,
    u16* __restrict__ C, int ldc, int K,
    const float* __restrict__ a2w, const float* __restrict__ a2b, float* __restrict__ aln)
{
    __shared__ __align__(16) u16 sA[4096];   // [128][32]
    __shared__ __align__(16) u16 sB[4096];   // [128][32]

    const int tid  = threadIdx.x;
    const int lane = tid & 63;
    const int wid  = tid >> 6;
    const int wr   = wid >> 1, wc = wid & 1;
    const int row0 = blockIdx.x << 7, col0 = blockIdx.y << 7;

    const int e0 = tid << 3,          r0s = e0 >> 5, c0s = e0 & 31;
    const int e1 = (256 + tid) << 3,  r1s = e1 >> 5, c1s = e1 & 31;
    const u16* gA0 = A + (size_t)(row0 + r0s)*lda + c0s;
    const u16* gA1 = A + (size_t)(row0 + r1s)*lda + c1s;
    const u16* gB0 = W + (size_t)(col0 + r0s)*ldw + c0s;
    const u16* gB1 = W + (size_t)(col0 + r1s)*ldw + c1s;
    u16* lA0 = sA + (wid << 9);
    u16* lA1 = sA + 2048 + (wid << 9);
    u16* lB0 = sB + (wid << 9);
    u16* lB1 = sB + 2048 + (wid << 9);

    const int la  = lane & 15;
    const int lk  = (lane >> 4) << 3;
    const int hi4 = (lane >> 4) << 2;
    const u16* rA = sA + (((wr << 6) + la) << 5) + lk;
    const u16* rB = sB + (((wc << 6) + la) << 5) + lk;

    f32x4 acc[4][4];
    {
        f32x4 binit[4];
        #pragma unroll
        for (int n=0;n<4;n++){
            float4 b4 = *reinterpret_cast<const float4*>(bias + col0 + (wc<<6) + (n<<4) + hi4);
            binit[n] = (f32x4){b4.x, b4.y, b4.z, b4.w};
        }
        #pragma unroll
        for (int m=0;m<4;m++)
            #pragma unroll
            for (int n=0;n<4;n++) acc[m][n] = binit[n];
    }

    for (int k0 = 0; k0 < K; k0 += 32){
        gload16(gA0 + k0, lA0);
        gload16(gA1 + k0, lA1);
        gload16(gB0 + k0, lB0);
        gload16(gB1 + k0, lB1);
        __syncthreads();
        bf16x8 af[4], bf[4];
        #pragma unroll
        for (int m=0;m<4;m++) af[m] = *reinterpret_cast<const bf16x8*>(rA + (m << 9));
        #pragma unroll
        for (int n=0;n<4;n++) bf[n] = *reinterpret_cast<const bf16x8*>(rB + (n << 9));
        #pragma unroll
        for (int m=0;m<4;m++)
            #pragma unroll
            for (int n=0;n<4;n++)
                acc[m][n] = __builtin_amdgcn_mfma_f32_16x16x32_bf16(bf[n], af[m], acc[m][n], 0, 0, 0);
        __syncthreads();
    }

    if (ACT == 2){
        // fused: alignment[row] = sigmoid( sum_col gelu(val)*a2w[col] + a2b )
        float w4[4][4];
        #pragma unroll
        for (int n=0;n<4;n++){
            float4 t4 = *reinterpret_cast<const float4*>(a2w + (wc<<6) + (n<<4) + hi4);
            w4[n][0]=t4.x; w4[n][1]=t4.y; w4[n][2]=t4.z; w4[n][3]=t4.w;
        }
        float* red = reinterpret_cast<float*>(sA);   // [128 rows][8 slots], 4KB
        #pragma unroll
        for (int m=0;m<4;m++){
            float p = 0.f;
            #pragma unroll
            for (int n=0;n<4;n++){
                f32x4 v = acc[m][n];
                p += gelu_f(v[0])*w4[n][0] + gelu_f(v[1])*w4[n][1]
                   + gelu_f(v[2])*w4[n][2] + gelu_f(v[3])*w4[n][3];
            }
            red[(((wr<<6) + (m<<4) + la) << 3) + (wc<<2) + (lane>>4)] = p;
        }
        __syncthreads();
        if (tid < 128){
            float s = 0.f;
            #pragma unroll
            for (int k2=0;k2<8;k2++) s += red[(tid<<3)+k2];
            aln[row0 + tid] = 1.0f/(1.0f + __expf(-(s + a2b[0])));
        }
        return;
    }

    #pragma unroll
    for (int m=0;m<4;m++){
        const int grow = row0 + (wr << 6) + (m << 4) + la;
        u16* crow = C + (size_t)grow*ldc + col0 + (wc << 6) + hi4;
        #pragma unroll
        for (int n=0;n<4;n++){
            f32x4 v = acc[m][n];
            float x0=v[0], x1=v[1], x2=v[2], x3=v[3];
            if (ACT == 1){ x0=gelu_f(x0); x1=gelu_f(x1); x2=gelu_f(x2); x3=gelu_f(x3); }
            ushort4 o; o.x=f2bf(x0); o.y=f2bf(x1); o.z=f2bf(x2); o.w=f2bf(x3);
            *reinterpret_cast<ushort4*>(crow + (n << 4)) = o;
        }
    }
}

// ---------------- 256x256 MFMA GEMM, BK=64, 2-buf, 4 phases/tile, no setprio (r14 engine) ----------------
template<int ACT>
__global__ __launch_bounds__(512) void gemm256p_kernel(
    const u16* __restrict__ A, int lda,
    const u16* __restrict__ W, int ldw,
    const float* __restrict__ bias,
    u16* __restrict__ C, int ldc, int K)
{
    __shared__ __align__(16) u16 sT[65536];   // 128 KiB

    const int tid  = threadIdx.x;
    const int lane = tid & 63;
    const int wid  = tid >> 6;            // 0..7
    const int wr   = wid >> 2;            // 0..1
    const int wc   = wid & 3;             // 0..3
    const int row0 = blockIdx.x << 8, col0 = blockIdx.y << 8;

    const int la = lane & 15;
    const int hi = lane >> 4;

    f32x4 acc[8][4];
    {
        f32x4 binit[4];
        #pragma unroll
        for (int n=0;n<4;n++){
            float4 b4 = *reinterpret_cast<const float4*>(bias + col0 + (wc<<6) + (n<<4) + (hi<<2));
            binit[n] = (f32x4){b4.x, b4.y, b4.z, b4.w};
        }
        #pragma unroll
        for (int m=0;m<8;m++)
            #pragma unroll
            for (int n=0;n<4;n++) acc[m][n] = binit[n];
    }

    const int rs = (wid << 4) + (lane >> 3);
    const int cs = ((lane & 7) ^ ((lane >> 3) & 7)) << 3;
    const u16* gA0 = A + (size_t)(row0 + rs)*lda + cs;
    const u16* gA1 = gA0 + (size_t)128*lda;
    const u16* gB0 = W + (size_t)(col0 + rs)*ldw + cs;
    const u16* gB1 = gB0 + (size_t)128*ldw;
    const int ldsw = (wid << 4) * 64;

    const int cph0 = (hi ^ (la & 7)) << 3;
    const u16* rAbase = sT + ((wr << 7) + la)*64;
    const u16* rBbase = sT + 16384 + ((wc << 6) + la)*64;

    const int NT = K >> 6;

    gload16(gB0, sT + 16384 + ldsw);          gload16(gB0 + 8*(size_t)ldw, sT + 16384 + ldsw + 512);
    gload16(gB1, sT + 24576 + ldsw);          gload16(gB1 + 8*(size_t)ldw, sT + 24576 + ldsw + 512);
    gload16(gA0, sT + ldsw);                  gload16(gA0 + 8*(size_t)lda, sT + ldsw + 512);
    gload16(gA1, sT + 8192 + ldsw);           gload16(gA1 + 8*(size_t)lda, sT + 8192 + ldsw + 512);

#define STG(GP, LD, DOFF) \
        gload16(GP + kb, sT + bn + (DOFF) + ldsw); \
        gload16(GP + kb + 8*(size_t)(LD), sT + bn + (DOFF) + ldsw + 512);

#define DSRA(MH, CO) { \
        const u16* rA_ = rAbase + b + ((MH) << 12) + (CO); \
        af[0] = *reinterpret_cast<const bf16x8*>(rA_); \
        af[1] = *reinterpret_cast<const bf16x8*>(rA_ + 1024); \
        af[2] = *reinterpret_cast<const bf16x8*>(rA_ + 2048); \
        af[3] = *reinterpret_cast<const bf16x8*>(rA_ + 3072); }

#define DSRB(CO) { \
        const u16* rB_ = rBbase + b + (CO); \
        bf[0] = *reinterpret_cast<const bf16x8*>(rB_); \
        bf[1] = *reinterpret_cast<const bf16x8*>(rB_ + 1024); \
        bf[2] = *reinterpret_cast<const bf16x8*>(rB_ + 2048); \
        bf[3] = *reinterpret_cast<const bf16x8*>(rB_ + 3072); }

#define MFMA16(MB) { \
        _Pragma("unroll") \
        for (int m=0;m<4;m++){ \
            _Pragma("unroll") \
            for (int n=0;n<4;n++) \
                acc[(MB)+m][n] = __builtin_amdgcn_mfma_f32_16x16x32_bf16(bf[n], af[m], acc[(MB)+m][n], 0,0,0); \
        } }

    for (int t = 0; t < NT; ++t){
        const int b  = (t & 1) << 15;
        const int bn = b ^ 32768;
        const bool stg = (t + 1 < NT);
        const int kb = (t + 1) << 6;
        bf16x8 af[4], bf[4];
        const int co0 = cph0;
        const int co1 = cph0 ^ 32;

        asm volatile("s_waitcnt vmcnt(0)" ::: "memory");
        __builtin_amdgcn_s_barrier();
        __builtin_amdgcn_sched_barrier(0);
        DSRB(co0)
        DSRA(0, co0)
        if (stg){ STG(gB0, ldw, 16384) }
        MFMA16(0)
        DSRA(1, co0)
        if (stg){ STG(gB1, ldw, 24576) }
        __builtin_amdgcn_sched_barrier(0);
        __builtin_amdgcn_s_barrier();
        __builtin_amdgcn_sched_barrier(0);
        MFMA16(4)
        DSRB(co1)
        DSRA(0, co1)
        if (stg){ STG(gA0, lda, 0) }
        __builtin_amdgcn_sched_barrier(0);
        __builtin_amdgcn_s_barrier();
        __builtin_amdgcn_sched_barrier(0);
        MFMA16(0)
        DSRA(1, co1)
        if (stg){ STG(gA1, lda, 8192) }
        __builtin_amdgcn_sched_barrier(0);
        __builtin_amdgcn_s_barrier();
        __builtin_amdgcn_sched_barrier(0);
        MFMA16(4)
    }
#undef STG
#undef DSRA
#undef DSRB
#undef MFMA16

    #pragma unroll
    for (int m=0;m<8;m++){
        const int grow = row0 + (wr << 7) + (m << 4) + la;
        u16* crow = C + (size_t)grow*ldc + col0 + (wc << 6) + (hi << 2);
        #pragma unroll
        for (int n=0;n<4;n++){
            f32x4 v = acc[m][n];
            float x0=v[0], x1=v[1], x2=v[2], x3=v[3];
            if (ACT == 1){ x0=gelu_f(x0); x1=gelu_f(x1); x2=gelu_f(x2); x3=gelu_f(x3); }
            ushort4 o; o.x=f2bf(x0); o.y=f2bf(x1); o.z=f2bf(x2); o.w=f2bf(x3);
            *reinterpret_cast<ushort4*>(crow + (n << 4)) = o;
        }
    }
}

// ---------------- FUSED: attention + out_proj + LN+FiLM (r15-verified) -> entry (overwrites wcat[b][0]) ----------------
// Block = 16 samples, 256 threads (4 waves). Grid = 2048.
__global__ __launch_bounds__(256) void attnop_kernel(
    const u16* __restrict__ q, const u16* __restrict__ kv,
    u16* __restrict__ wcat,
    const u16* __restrict__ opw, const float* __restrict__ opb,
    const float* __restrict__ regime,
    const float* __restrict__ sgw, const float* __restrict__ sgb,
    const float* __restrict__ sbw, const float* __restrict__ sbb,
    const float* __restrict__ g1, const float* __restrict__ b1)
{
    __shared__ __align__(16) u16 sKV[32768];      // 16 x 2048 (k|v per n); later sAO = f32[16][264]
    __shared__ __align__(16) u16 sQC[16*264];     // q then ctx, row stride 264
    __shared__ float sAT[256];                    // attn weights (s*16 + h*4 + n)

    const int t  = threadIdx.x;
    const int b0 = blockIdx.x << 4;

    // ---- load q + kv ----
    {
        const int row = t >> 4, u = t & 15;
        const u16* qsrc = q + (size_t)(b0 + row)*256 + (u << 4);
        *reinterpret_cast<bf16x8*>(sQC + row*264 + (u<<4))     = *reinterpret_cast<const bf16x8*>(qsrc);
        *reinterpret_cast<bf16x8*>(sQC + row*264 + (u<<4) + 8) = *reinterpret_cast<const bf16x8*>(qsrc + 8);
        const u16* kvsrc = kv + (size_t)b0*2048;
        #pragma unroll
        for (int j=0;j<16;j++){
            const int off = (t<<3) + j*2048;
            *reinterpret_cast<bf16x8*>(sKV + off) = *reinterpret_cast<const bf16x8*>(kvsrc + off);
        }
    }
    __syncthreads();

    // ---- scores + softmax: thread t = (s, h, n); shfl over n ----
    {
        const int s = t >> 4, h = (t >> 2) & 3, n = t & 3;
        float sc = 0.f;
        const u16* qp = sQC + s*264 + h*64;
        const u16* kp = sKV + s*2048 + n*512 + h*64;
        #pragma unroll
        for (int dh=0; dh<64; ++dh) sc += bf2f(qp[dh]) * bf2f(kp[dh]);
        sc *= 0.125f;
        float m = fmaxf(sc, __shfl_xor(sc, 1)); m = fmaxf(m, __shfl_xor(m, 2));
        float e = __expf(sc - m);
        float sum = e + __shfl_xor(e, 1); sum += __shfl_xor(sum, 2);
        sAT[t] = e / sum;
    }
    __syncthreads();

    // ---- ctx[s][d] -> sQC ----
    {
        const int s = t >> 4, u = t & 15;
        #pragma unroll
        for (int j=0;j<16;j++){
            const int d = (u << 4) + j;
            const int h = d >> 6;
            const float* a = sAT + s*16 + (h<<2);
            const u16* vp = sKV + s*2048 + 256 + d;
            float c = a[0]*bf2f(vp[0]) + a[1]*bf2f(vp[512]) + a[2]*bf2f(vp[1024]) + a[3]*bf2f(vp[1536]);
            sQC[s*264 + d] = f2bf(c);
        }
    }
    __syncthreads();   // ctx visible; kv dead

    // ---- ao = ctx @ opw^T + opb via MFMA ----
    float* sAO = reinterpret_cast<float*>(sKV);   // f32 [16][264]
    {
        const int lane = t & 63, wid = t >> 6;
        const int la = lane & 15, hi = lane >> 4;
        f32x4 acc[4];
        #pragma unroll
        for (int n=0;n<4;n++){
            float4 b4 = *reinterpret_cast<const float4*>(opb + (wid<<6) + (n<<4) + (hi<<2));
            acc[n] = (f32x4){b4.x, b4.y, b4.z, b4.w};
        }
        #pragma unroll
        for (int ks=0; ks<8; ++ks){
            bf16x8 af = *reinterpret_cast<const bf16x8*>(sQC + la*264 + (ks<<5) + (hi<<3));
            #pragma unroll
            for (int n=0;n<4;n++){
                bf16x8 wf = *reinterpret_cast<const bf16x8*>(
                    opw + (size_t)((wid<<6) + (n<<4) + la)*256 + (ks<<5) + (hi<<3));
                acc[n] = __builtin_amdgcn_mfma_f32_16x16x32_bf16(wf, af, acc[n], 0, 0, 0);
            }
        }
        #pragma unroll
        for (int n=0;n<4;n++){
            float4 st = {acc[n][0], acc[n][1], acc[n][2], acc[n][3]};
            *reinterpret_cast<float4*>(sAO + la*264 + (wid<<6) + (n<<4) + (hi<<2)) = st;
        }
    }
    __syncthreads();

    // ---- entry = FiLM(LN(query + ao)) -> wcat row 0 ----
    {
        const int s = t >> 4, u = t & 15;
        u16* qrow = wcat + (size_t)(b0 + s)*1024;
        float xv[16], sum = 0.f, sq = 0.f;
        #pragma unroll
        for (int j=0;j<16;j++){
            const int d = u + (j << 4);
            float x = sAO[s*264 + d] + bf2f(qrow[d]);
            xv[j] = x; sum += x; sq += x*x;
        }
        #pragma unroll
        for (int o=1;o<16;o<<=1){ sum += __shfl_xor(sum, o); sq += __shfl_xor(sq, o); }
        float mu   = sum * (1.0f/256.0f);
        float var  = sq  * (1.0f/256.0f) - mu*mu;
        float rstd = rsqrtf(var + 1e-5f);
        const float r0 = regime[(b0+s)*4+0], r1 = regime[(b0+s)*4+1];
        const float r2 = regime[(b0+s)*4+2], r3 = regime[(b0+s)*4+3];
        #pragma unroll
        for (int j=0;j<16;j++){
            const int d = u + (j << 4);
            float gam = r0*sgw[d*4+0] + r1*sgw[d*4+1] + r2*sgw[d*4+2] + r3*sgw[d*4+3] + sgb[d];
            float bet = r0*sbw[d*4+0] + r1*sbw[d*4+1] + r2*sbw[d*4+2] + r3*sbw[d*4+3] + sbb[d];
            float e = ((xv[j]-mu)*rstd*g1[d] + b1[d])*(1.0f+gam) + bet;
            qrow[d] = f2bf(e);
        }
    }
}

// ---------------- FUSED f2 GEMM (128 x 512, BK=32) + LN2 -> f32 out (r16-verified) ----------------
__global__ __launch_bounds__(512) void f2ln_kernel(
    const u16* __restrict__ A,            // hbuf [32768][1024]
    const u16* __restrict__ W,            // f2w  [512][1024]
    const float* __restrict__ bias,       // f2_b [512]
    const float* __restrict__ g, const float* __restrict__ bt,   // ln2
    float* __restrict__ out)              // [32768][512] f32
{
    __shared__ __align__(16) u16 sT[66560];

    const int tid  = threadIdx.x;
    const int lane = tid & 63;
    const int wid  = tid >> 6;            // 0..7
    const int wr   = wid >> 2;            // 0..1 (rows)
    const int wc   = wid & 3;             // 0..3 (cols)
    const int row0 = blockIdx.x << 7;

    const int la = lane & 15;
    const int hi = lane >> 4;

    f32x4 acc[4][8];
    {
        #pragma unroll
        for (int n=0;n<8;n++){
            float4 b4 = *reinterpret_cast<const float4*>(bias + (wc<<7) + (n<<4) + (hi<<2));
            f32x4 bi = (f32x4){b4.x, b4.y, b4.z, b4.w};
            #pragma unroll
            for (int m=0;m<4;m++) acc[m][n] = bi;
        }
    }

    const int rsA = (wid << 4) + (lane >> 2);
    const int rsB = (wid << 6) + (lane >> 2);
    const int swA = ((lane & 3) ^ ((rsA >> 1) & 3)) << 3;
    const int swB = ((lane & 3) ^ ((rsB >> 1) & 3)) << 3;
    const u16* pA = A + (size_t)(row0 + rsA)*1024 + swA;
    const u16* pB = W + (size_t)rsB*1024 + swB;

    const int cph0 = (hi ^ ((la >> 1) & 3)) << 3;

    const int NT = 32;   // K=1024 / 32

    gload16(pA, sT + (wid<<9));
    #pragma unroll
    for (int j=0;j<4;j++) gload16(pB + (size_t)(j<<4)*1024, sT + 4096 + (wid<<11) + (j<<9));

    for (int t = 0; t < NT; ++t){
        const int b  = (t & 1) ? 20480 : 0;
        const int bn = b ? 0 : 20480;
        const int kb = (t + 1) << 5;

        asm volatile("s_waitcnt vmcnt(0)" ::: "memory");
        __builtin_amdgcn_s_barrier();
        __builtin_amdgcn_sched_barrier(0);

        if (t + 1 < NT){
            gload16(pA + kb, sT + bn + (wid<<9));
            #pragma unroll
            for (int j=0;j<4;j++) gload16(pB + (size_t)(j<<4)*1024 + kb, sT + bn + 4096 + (wid<<11) + (j<<9));
        }

        bf16x8 af[4], bf[8];
        #pragma unroll
        for (int m=0;m<4;m++){
            const int r = (wr<<6) + (m<<4) + la;
            af[m] = *reinterpret_cast<const bf16x8*>(sT + b + (r<<5) + cph0);
        }
        #pragma unroll
        for (int n=0;n<8;n++){
            const int r = (wc<<7) + (n<<4) + la;
            bf[n] = *reinterpret_cast<const bf16x8*>(sT + b + 4096 + (r<<5) + cph0);
        }
        #pragma unroll
        for (int m=0;m<4;m++)
            #pragma unroll
            for (int n=0;n<8;n++)
                acc[m][n] = __builtin_amdgcn_mfma_f32_16x16x32_bf16(bf[n], af[m], acc[m][n], 0, 0, 0);
    }

    // ---- epilogue: acc -> LDS bf16 [128][520], per-row LN, write f32 out ----
    __builtin_amdgcn_s_barrier();
    #pragma unroll
    for (int m=0;m<4;m++){
        const int r = (wr<<6) + (m<<4) + la;
        u16* rowp = sT + r*520 + (wc<<7) + (hi<<2);
        #pragma unroll
        for (int n=0;n<8;n++){
            ushort4 o;
            o.x = f2bf(acc[m][n][0]); o.y = f2bf(acc[m][n][1]);
            o.z = f2bf(acc[m][n][2]); o.w = f2bf(acc[m][n][3]);
            *reinterpret_cast<ushort4*>(rowp + (n<<4)) = o;
        }
    }
    __syncthreads();

    {
        const int r  = tid >> 2;        // 0..127
        const int q4 = tid & 3;         // quarter
        const u16* rowp = sT + r*520 + (q4<<7);
        float sum = 0.f, sq = 0.f;
        #pragma unroll
        for (int i=0;i<16;i++){
            bf16x8 v = *reinterpret_cast<const bf16x8*>(rowp + (i<<3));
            #pragma unroll
            for (int k=0;k<8;k++){ float x = bf2f((u16)v[k]); sum += x; sq += x*x; }
        }
        sum += __shfl_xor(sum, 1); sq += __shfl_xor(sq, 1);
        sum += __shfl_xor(sum, 2); sq += __shfl_xor(sq, 2);
        float mu   = sum * (1.0f/512.0f);
        float var  = sq  * (1.0f/512.0f) - mu*mu;
        float rstd = rsqrtf(var + 1e-5f);
        float* orow = out + (size_t)(row0 + r)*512 + (q4<<7);
        #pragma unroll
        for (int i=0;i<16;i++){
            bf16x8 v = *reinterpret_cast<const bf16x8*>(rowp + (i<<3));
            const int c0 = (q4<<7) + (i<<3);
            float4 o0, o1;
            o0.x = (bf2f((u16)v[0])-mu)*rstd*g[c0+0] + bt[c0+0];
            o0.y = (bf2f((u16)v[1])-mu)*rstd*g[c0+1] + bt[c0+1];
            o0.z = (bf2f((u16)v[2])-mu)*rstd*g[c0+2] + bt[c0+2];
            o0.w = (bf2f((u16)v[3])-mu)*rstd*g[c0+3] + bt[c0+3];
            o1.x = (bf2f((u16)v[4])-mu)*rstd*g[c0+4] + bt[c0+4];
            o1.y = (bf2f((u16)v[5])-mu)*rstd*g[c0+5] + bt[c0+5];
            o1.z = (bf2f((u16)v[6])-mu)*rstd*g[c0+6] + bt[c0+6];
            o1.w = (bf2f((u16)v[7])-mu)*rstd*g[c0+7] + bt[c0+7];
            *reinterpret_cast<float4*>(orow + (i<<3))     = o0;
            *reinterpret_cast<float4*>(orow + (i<<3) + 4) = o1;
        }
    }
}

extern "C" void kernel_launch(void* const* d_in, const int* in_sizes, int n_in,
                              void* d_out, int out_size, void* d_ws, size_t ws_size,
                              hipStream_t stream) {
    const float* w0   = (const float*)d_in[0];
    const float* w1   = (const float*)d_in[1];
    const float* w2   = (const float*)d_in[2];
    const float* w3   = (const float*)d_in[3];
    const float* regime = (const float*)d_in[4];
    const float* tfw  = (const float*)d_in[5];
    const float* in_proj_w = (const float*)d_in[6];
    const float* in_proj_b = (const float*)d_in[7];
    const float* out_proj_w = (const float*)d_in[8];
    const float* out_proj_b = (const float*)d_in[9];
    const float* ln1_g = (const float*)d_in[10];
    const float* ln1_b = (const float*)d_in[11];
    const float* sg_w = (const float*)d_in[12];
    const float* sg_b = (const float*)d_in[13];
    const float* sb_w = (const float*)d_in[14];
    const float* sb_b = (const float*)d_in[15];
    const float* f1_w = (const float*)d_in[16];
    const float* f1_b = (const float*)d_in[17];
    const float* f2_w = (const float*)d_in[18];
    const float* f2_b = (const float*)d_in[19];
    const float* ln2_g = (const float*)d_in[20];
    const float* ln2_b = (const float*)d_in[21];
    const float* a1_w = (const float*)d_in[22];
    const float* a1_b = (const float*)d_in[23];
    const float* a2_w = (const float*)d_in[24];
    const float* a2_b = (const float*)d_in[25];

    char* ws = (char*)d_ws;
    u16* wcat  = (u16*)(ws);
    u16* qbuf  = (u16*)(ws + 67108864ull);     // 64..80Mi
    u16* kvbuf = (u16*)(ws + 83886080ull);     // 80..208Mi
    u16* hbuf  = kvbuf;                        // 80..144Mi after attnop
    u16* wb    = (u16*)(ws + 218103808ull);
    u16* ipw = wb;                // 196608 elems
    u16* opw = wb + 196608;       // 65536
    u16* f1w = wb + 262144;       // 1048576
    u16* f2w = wb + 1310720;      // 524288
    u16* a1w = wb + 1835008;      // 131072

    float* out_fused = (float*)d_out;
    float* out_align = (float*)d_out + (size_t)NB*512;

    // 1. prep + all weight conversions
    prepconv_kernel<<<10112, 256, 0, stream>>>(w0,w1,w2,w3,tfw,wcat,
        in_proj_w,ipw, out_proj_w,opw, f1_w,f1w, f2_w,f2w, a1_w,a1w);
    // 2. q = query @ wq^T + bq
    mgemm_kernel<0><<<dim3(256, 2), 256, 0, stream>>>(wcat, 1024, ipw, 256, in_proj_b, qbuf, 256, 256, nullptr, nullptr, nullptr);
    // 3. kv = weighted @ [wk;wv]^T + b
    gemm256p_kernel<0><<<dim3(512, 2), 512, 0, stream>>>(wcat, 256, ipw+65536, 256, in_proj_b+256, kvbuf, 512, 256);
    // 4. FUSED attention + out_proj + LN+FiLM -> wcat entry rows
    attnop_kernel<<<2048, 256, 0, stream>>>(qbuf, kvbuf, wcat, opw, out_proj_b,
        regime, sg_w, sg_b, sb_w, sb_b, ln1_g, ln1_b);
    // 5. h = gelu(cat @ f1^T + b) -> hbuf
    gemm256p_kernel<1><<<dim3(128, 4), 512, 0, stream>>>(wcat, 1024, f1w, 1024, f1_b, hbuf, 1024, 1024);
    // 6. FUSED t1 = h @ f2^T + b, fused = LN(t1) -> out
    f2ln_kernel<<<256, 512, 0, stream>>>(hbuf, f2w, f2_b, ln2_g, ln2_b, out_fused);
    // 7. alignment = sigmoid(gelu(cat @ a1^T + b) @ a2^T + b)
    mgemm_kernel<2><<<dim3(256, 1), 256, 0, stream>>>(wcat, 1024, a1w, 1024, a1_b, qbuf, 128, 1024, a2_w, a2_b, out_align);
}

// Round 18
// 339.180 us; speedup vs baseline: 1.0824x; 1.0302x over previous
//
#include <hip/hip_runtime.h>
#include <math.h>

#define NB 32768   // batch
// D=256, N=4, OUT=512, H=4, DH=64

typedef unsigned short u16;
typedef __attribute__((ext_vector_type(4))) float f32x4;
typedef __attribute__((ext_vector_type(8))) short bf16x8;

__device__ __forceinline__ float bf2f(u16 u){ return __uint_as_float(((unsigned int)u)<<16); }
__device__ __forceinline__ u16 f2bf(float f){
    unsigned int x = __float_as_uint(f);
    x += 0x7fffu + ((x>>16)&1u);   // round-to-nearest-even
    return (u16)(x>>16);
}
// gelu exact-erf via A&S 7.1.26 (|eps|<=1.5e-7), branchless: rcp + exp + 5 fma
__device__ __forceinline__ float gelu_f(float x){
    float z = fabsf(x) * 0.70710678118654752f;
    float t = __builtin_amdgcn_rcpf(1.0f + 0.3275911f*z);
    float p = t*(0.254829592f + t*(-0.284496736f + t*(1.421413741f + t*(-1.453152027f + t*1.061405429f))));
    float e = __expf(-z*z);
    float erf_abs = 1.0f - p*e;
    float erfv = copysignf(erf_abs, x);
    return 0.5f*x*(1.0f + erfv);
}

__device__ __forceinline__ void gload16(const void* g, void* l){
    __builtin_amdgcn_global_load_lds(
        (const __attribute__((address_space(1))) unsigned int*)g,
        (__attribute__((address_space(3))) unsigned int*)l, 16, 0, 0);
}

// ---------------- prep (scale w0..w3 by softmax(tfw)) + all weight fp32->bf16 conversions ----------------
__global__ __launch_bounds__(256) void prepconv_kernel(
    const float* __restrict__ w0, const float* __restrict__ w1,
    const float* __restrict__ w2, const float* __restrict__ w3,
    const float* __restrict__ tfw, u16* __restrict__ wcat,
    const float* __restrict__ ipw_s, u16* __restrict__ ipw_d,
    const float* __restrict__ op_s,  u16* __restrict__ op_d,
    const float* __restrict__ f1_s,  u16* __restrict__ f1_d,
    const float* __restrict__ f2_s,  u16* __restrict__ f2_d,
    const float* __restrict__ a1_s,  u16* __restrict__ a1_d)
{
    const int blk = blockIdx.x, tid = threadIdx.x;
    if (blk < 8192){
        float t0=tfw[0], t1=tfw[1], t2=tfw[2], t3=tfw[3];
        float m = fmaxf(fmaxf(t0,t1), fmaxf(t2,t3));
        float e0=expf(t0-m), e1=expf(t1-m), e2=expf(t2-m), e3=expf(t3-m);
        float inv = 1.0f/(e0+e1+e2+e3);
        float s0=e0*inv, s1=e1*inv, s2=e2*inv, s3=e3*inv;

        int idx = blk*256 + tid;
        int b  = idx >> 6;
        int d4 = (idx & 63) << 2;
        size_t src = (size_t)b*256 + d4;
        float4 a0 = *reinterpret_cast<const float4*>(w0 + src);
        float4 a1 = *reinterpret_cast<const float4*>(w1 + src);
        float4 a2 = *reinterpret_cast<const float4*>(w2 + src);
        float4 a3 = *reinterpret_cast<const float4*>(w3 + src);
        size_t dst = (size_t)b*1024 + d4;
        ushort4 o;
        o.x=f2bf(a0.x*s0); o.y=f2bf(a0.y*s0); o.z=f2bf(a0.z*s0); o.w=f2bf(a0.w*s0);
        *reinterpret_cast<ushort4*>(wcat + dst) = o;
        o.x=f2bf(a1.x*s1); o.y=f2bf(a1.y*s1); o.z=f2bf(a1.z*s1); o.w=f2bf(a1.w*s1);
        *reinterpret_cast<ushort4*>(wcat + dst + 256) = o;
        o.x=f2bf(a2.x*s2); o.y=f2bf(a2.y*s2); o.z=f2bf(a2.z*s2); o.w=f2bf(a2.w*s2);
        *reinterpret_cast<ushort4*>(wcat + dst + 512) = o;
        o.x=f2bf(a3.x*s3); o.y=f2bf(a3.y*s3); o.z=f2bf(a3.z*s3); o.w=f2bf(a3.w*s3);
        *reinterpret_cast<ushort4*>(wcat + dst + 768) = o;
    } else {
        int i = (blk - 8192)*256 + tid;   // float4 index across all weights
        const float* s; u16* d; int off;
        if      (i < 49152)  { s=ipw_s; d=ipw_d; off=i; }
        else if (i < 65536)  { s=op_s;  d=op_d;  off=i-49152; }
        else if (i < 327680) { s=f1_s;  d=f1_d;  off=i-65536; }
        else if (i < 458752) { s=f2_s;  d=f2_d;  off=i-327680; }
        else                 { s=a1_s;  d=a1_d;  off=i-458752; }
        float4 v = reinterpret_cast<const float4*>(s)[off];
        ushort4 o; o.x=f2bf(v.x); o.y=f2bf(v.y); o.z=f2bf(v.z); o.w=f2bf(v.w);
        reinterpret_cast<ushort4*>(d)[off] = o;
    }
}

// ---------------- 128x128 MFMA GEMM. ACT: 0 none, 1 gelu, 2 gelu + fused a2 row-dot ----------------
template<int ACT>
__global__ __launch_bounds__(256) void mgemm_kernel(
    const u16* __restrict__ A, int lda,
    const u16* __restrict__ W, int ldw,
    const float* __restrict__ bias,
    u16* __restrict__ C, int ldc, int K,
    const float* __restrict__ a2w, const float* __restrict__ a2b, float* __restrict__ aln)
{
    __shared__ __align__(16) u16 sA[4096];   // [128][32]
    __shared__ __align__(16) u16 sB[4096];   // [128][32]

    const int tid  = threadIdx.x;
    const int lane = tid & 63;
    const int wid  = tid >> 6;
    const int wr   = wid >> 1, wc = wid & 1;
    const int row0 = blockIdx.x << 7, col0 = blockIdx.y << 7;

    const int e0 = tid << 3,          r0s = e0 >> 5, c0s = e0 & 31;
    const int e1 = (256 + tid) << 3,  r1s = e1 >> 5, c1s = e1 & 31;
    const u16* gA0 = A + (size_t)(row0 + r0s)*lda + c0s;
    const u16* gA1 = A + (size_t)(row0 + r1s)*lda + c1s;
    const u16* gB0 = W + (size_t)(col0 + r0s)*ldw + c0s;
    const u16* gB1 = W + (size_t)(col0 + r1s)*ldw + c1s;
    u16* lA0 = sA + (wid << 9);
    u16* lA1 = sA + 2048 + (wid << 9);
    u16* lB0 = sB + (wid << 9);
    u16* lB1 = sB + 2048 + (wid << 9);

    const int la  = lane & 15;
    const int lk  = (lane >> 4) << 3;
    const int hi4 = (lane >> 4) << 2;
    const u16* rA = sA + (((wr << 6) + la) << 5) + lk;
    const u16* rB = sB + (((wc << 6) + la) << 5) + lk;

    f32x4 acc[4][4];
    {
        f32x4 binit[4];
        #pragma unroll
        for (int n=0;n<4;n++){
            float4 b4 = *reinterpret_cast<const float4*>(bias + col0 + (wc<<6) + (n<<4) + hi4);
            binit[n] = (f32x4){b4.x, b4.y, b4.z, b4.w};
        }
        #pragma unroll
        for (int m=0;m<4;m++)
            #pragma unroll
            for (int n=0;n<4;n++) acc[m][n] = binit[n];
    }

    for (int k0 = 0; k0 < K; k0 += 32){
        gload16(gA0 + k0, lA0);
        gload16(gA1 + k0, lA1);
        gload16(gB0 + k0, lB0);
        gload16(gB1 + k0, lB1);
        __syncthreads();
        bf16x8 af[4], bf[4];
        #pragma unroll
        for (int m=0;m<4;m++) af[m] = *reinterpret_cast<const bf16x8*>(rA + (m << 9));
        #pragma unroll
        for (int n=0;n<4;n++) bf[n] = *reinterpret_cast<const bf16x8*>(rB + (n << 9));
        #pragma unroll
        for (int m=0;m<4;m++)
            #pragma unroll
            for (int n=0;n<4;n++)
                acc[m][n] = __builtin_amdgcn_mfma_f32_16x16x32_bf16(bf[n], af[m], acc[m][n], 0, 0, 0);
        __syncthreads();
    }

    if (ACT == 2){
        // fused: alignment[row] = sigmoid( sum_col gelu(val)*a2w[col] + a2b )
        float w4[4][4];
        #pragma unroll
        for (int n=0;n<4;n++){
            float4 t4 = *reinterpret_cast<const float4*>(a2w + (wc<<6) + (n<<4) + hi4);
            w4[n][0]=t4.x; w4[n][1]=t4.y; w4[n][2]=t4.z; w4[n][3]=t4.w;
        }
        float* red = reinterpret_cast<float*>(sA);   // [128 rows][8 slots], 4KB
        #pragma unroll
        for (int m=0;m<4;m++){
            float p = 0.f;
            #pragma unroll
            for (int n=0;n<4;n++){
                f32x4 v = acc[m][n];
                p += gelu_f(v[0])*w4[n][0] + gelu_f(v[1])*w4[n][1]
                   + gelu_f(v[2])*w4[n][2] + gelu_f(v[3])*w4[n][3];
            }
            red[(((wr<<6) + (m<<4) + la) << 3) + (wc<<2) + (lane>>4)] = p;
        }
        __syncthreads();
        if (tid < 128){
            float s = 0.f;
            #pragma unroll
            for (int k2=0;k2<8;k2++) s += red[(tid<<3)+k2];
            aln[row0 + tid] = 1.0f/(1.0f + __expf(-(s + a2b[0])));
        }
        return;
    }

    #pragma unroll
    for (int m=0;m<4;m++){
        const int grow = row0 + (wr << 6) + (m << 4) + la;
        u16* crow = C + (size_t)grow*ldc + col0 + (wc << 6) + hi4;
        #pragma unroll
        for (int n=0;n<4;n++){
            f32x4 v = acc[m][n];
            float x0=v[0], x1=v[1], x2=v[2], x3=v[3];
            if (ACT == 1){ x0=gelu_f(x0); x1=gelu_f(x1); x2=gelu_f(x2); x3=gelu_f(x3); }
            ushort4 o; o.x=f2bf(x0); o.y=f2bf(x1); o.z=f2bf(x2); o.w=f2bf(x3);
            *reinterpret_cast<ushort4*>(crow + (n << 4)) = o;
        }
    }
}

// ---------------- 256x256 MFMA GEMM, BK=64, 2-buf, 4 phases/tile, no setprio (r14 engine) ----------------
template<int ACT>
__global__ __launch_bounds__(512) void gemm256p_kernel(
    const u16* __restrict__ A, int lda,
    const u16* __restrict__ W, int ldw,
    const float* __restrict__ bias,
    u16* __restrict__ C, int ldc, int K)
{
    __shared__ __align__(16) u16 sT[65536];   // 128 KiB

    const int tid  = threadIdx.x;
    const int lane = tid & 63;
    const int wid  = tid >> 6;            // 0..7
    const int wr   = wid >> 2;            // 0..1
    const int wc   = wid & 3;             // 0..3
    const int row0 = blockIdx.x << 8, col0 = blockIdx.y << 8;

    const int la = lane & 15;
    const int hi = lane >> 4;

    f32x4 acc[8][4];
    {
        f32x4 binit[4];
        #pragma unroll
        for (int n=0;n<4;n++){
            float4 b4 = *reinterpret_cast<const float4*>(bias + col0 + (wc<<6) + (n<<4) + (hi<<2));
            binit[n] = (f32x4){b4.x, b4.y, b4.z, b4.w};
        }
        #pragma unroll
        for (int m=0;m<8;m++)
            #pragma unroll
            for (int n=0;n<4;n++) acc[m][n] = binit[n];
    }

    const int rs = (wid << 4) + (lane >> 3);
    const int cs = ((lane & 7) ^ ((lane >> 3) & 7)) << 3;
    const u16* gA0 = A + (size_t)(row0 + rs)*lda + cs;
    const u16* gA1 = gA0 + (size_t)128*lda;
    const u16* gB0 = W + (size_t)(col0 + rs)*ldw + cs;
    const u16* gB1 = gB0 + (size_t)128*ldw;
    const int ldsw = (wid << 4) * 64;

    const int cph0 = (hi ^ (la & 7)) << 3;
    const u16* rAbase = sT + ((wr << 7) + la)*64;
    const u16* rBbase = sT + 16384 + ((wc << 6) + la)*64;

    const int NT = K >> 6;

    gload16(gB0, sT + 16384 + ldsw);          gload16(gB0 + 8*(size_t)ldw, sT + 16384 + ldsw + 512);
    gload16(gB1, sT + 24576 + ldsw);          gload16(gB1 + 8*(size_t)ldw, sT + 24576 + ldsw + 512);
    gload16(gA0, sT + ldsw);                  gload16(gA0 + 8*(size_t)lda, sT + ldsw + 512);
    gload16(gA1, sT + 8192 + ldsw);           gload16(gA1 + 8*(size_t)lda, sT + 8192 + ldsw + 512);

#define STG(GP, LD, DOFF) \
        gload16(GP + kb, sT + bn + (DOFF) + ldsw); \
        gload16(GP + kb + 8*(size_t)(LD), sT + bn + (DOFF) + ldsw + 512);

#define DSRA(MH, CO) { \
        const u16* rA_ = rAbase + b + ((MH) << 12) + (CO); \
        af[0] = *reinterpret_cast<const bf16x8*>(rA_); \
        af[1] = *reinterpret_cast<const bf16x8*>(rA_ + 1024); \
        af[2] = *reinterpret_cast<const bf16x8*>(rA_ + 2048); \
        af[3] = *reinterpret_cast<const bf16x8*>(rA_ + 3072); }

#define DSRB(CO) { \
        const u16* rB_ = rBbase + b + (CO); \
        bf[0] = *reinterpret_cast<const bf16x8*>(rB_); \
        bf[1] = *reinterpret_cast<const bf16x8*>(rB_ + 1024); \
        bf[2] = *reinterpret_cast<const bf16x8*>(rB_ + 2048); \
        bf[3] = *reinterpret_cast<const bf16x8*>(rB_ + 3072); }

#define MFMA16(MB) { \
        _Pragma("unroll") \
        for (int m=0;m<4;m++){ \
            _Pragma("unroll") \
            for (int n=0;n<4;n++) \
                acc[(MB)+m][n] = __builtin_amdgcn_mfma_f32_16x16x32_bf16(bf[n], af[m], acc[(MB)+m][n], 0,0,0); \
        } }

    for (int t = 0; t < NT; ++t){
        const int b  = (t & 1) << 15;
        const int bn = b ^ 32768;
        const bool stg = (t + 1 < NT);
        const int kb = (t + 1) << 6;
        bf16x8 af[4], bf[4];
        const int co0 = cph0;
        const int co1 = cph0 ^ 32;

        asm volatile("s_waitcnt vmcnt(0)" ::: "memory");
        __builtin_amdgcn_s_barrier();
        __builtin_amdgcn_sched_barrier(0);
        DSRB(co0)
        DSRA(0, co0)
        if (stg){ STG(gB0, ldw, 16384) }
        MFMA16(0)
        DSRA(1, co0)
        if (stg){ STG(gB1, ldw, 24576) }
        __builtin_amdgcn_sched_barrier(0);
        __builtin_amdgcn_s_barrier();
        __builtin_amdgcn_sched_barrier(0);
        MFMA16(4)
        DSRB(co1)
        DSRA(0, co1)
        if (stg){ STG(gA0, lda, 0) }
        __builtin_amdgcn_sched_barrier(0);
        __builtin_amdgcn_s_barrier();
        __builtin_amdgcn_sched_barrier(0);
        MFMA16(0)
        DSRA(1, co1)
        if (stg){ STG(gA1, lda, 8192) }
        __builtin_amdgcn_sched_barrier(0);
        __builtin_amdgcn_s_barrier();
        __builtin_amdgcn_sched_barrier(0);
        MFMA16(4)
    }
#undef STG
#undef DSRA
#undef DSRB
#undef MFMA16

    #pragma unroll
    for (int m=0;m<8;m++){
        const int grow = row0 + (wr << 7) + (m << 4) + la;
        u16* crow = C + (size_t)grow*ldc + col0 + (wc << 6) + (hi << 2);
        #pragma unroll
        for (int n=0;n<4;n++){
            f32x4 v = acc[m][n];
            float x0=v[0], x1=v[1], x2=v[2], x3=v[3];
            if (ACT == 1){ x0=gelu_f(x0); x1=gelu_f(x1); x2=gelu_f(x2); x3=gelu_f(x3); }
            ushort4 o; o.x=f2bf(x0); o.y=f2bf(x1); o.z=f2bf(x2); o.w=f2bf(x3);
            *reinterpret_cast<ushort4*>(crow + (n << 4)) = o;
        }
    }
}

// ---------------- FUSED: attention + out_proj + LN+FiLM -> entry (overwrites wcat[b][0]) ----------------
// Block = 16 samples, 256 threads (4 waves). Grid = 2048. (r14-verified, bench 342.6)
__global__ __launch_bounds__(256) void attnop_kernel(
    const u16* __restrict__ q, const u16* __restrict__ kv,
    u16* __restrict__ wcat,
    const u16* __restrict__ opw, const float* __restrict__ opb,
    const float* __restrict__ regime,
    const float* __restrict__ sgw, const float* __restrict__ sgb,
    const float* __restrict__ sbw, const float* __restrict__ sbb,
    const float* __restrict__ g1, const float* __restrict__ b1)
{
    __shared__ __align__(16) u16 sKV[32768];      // 16 x 2048 (k|v per n); later sAO = f32[16][264]
    __shared__ __align__(16) u16 sQC[16*264];     // q then ctx, row stride 264
    __shared__ float sAT[256];                    // attn weights (s*16 + h*4 + n)

    const int t  = threadIdx.x;
    const int b0 = blockIdx.x << 4;

    // ---- load q + kv ----
    {
        const int row = t >> 4, u = t & 15;
        const u16* qsrc = q + (size_t)(b0 + row)*256 + (u << 4);
        *reinterpret_cast<bf16x8*>(sQC + row*264 + (u<<4))     = *reinterpret_cast<const bf16x8*>(qsrc);
        *reinterpret_cast<bf16x8*>(sQC + row*264 + (u<<4) + 8) = *reinterpret_cast<const bf16x8*>(qsrc + 8);
        const u16* kvsrc = kv + (size_t)b0*2048;
        #pragma unroll
        for (int j=0;j<16;j++){
            const int off = (t<<3) + j*2048;
            *reinterpret_cast<bf16x8*>(sKV + off) = *reinterpret_cast<const bf16x8*>(kvsrc + off);
        }
    }
    __syncthreads();

    // ---- scores + softmax: thread t = (s, h, n); shfl over n ----
    {
        const int s = t >> 4, h = (t >> 2) & 3, n = t & 3;
        float sc = 0.f;
        const u16* qp = sQC + s*264 + h*64;
        const u16* kp = sKV + s*2048 + n*512 + h*64;
        #pragma unroll
        for (int dh=0; dh<64; ++dh) sc += bf2f(qp[dh]) * bf2f(kp[dh]);
        sc *= 0.125f;
        float m = fmaxf(sc, __shfl_xor(sc, 1)); m = fmaxf(m, __shfl_xor(m, 2));
        float e = __expf(sc - m);
        float sum = e + __shfl_xor(e, 1); sum += __shfl_xor(sum, 2);
        sAT[t] = e / sum;
    }
    __syncthreads();

    // ---- ctx[s][d] -> sQC ----
    {
        const int s = t >> 4, u = t & 15;
        #pragma unroll
        for (int j=0;j<16;j++){
            const int d = (u << 4) + j;
            const int h = d >> 6;
            const float* a = sAT + s*16 + (h<<2);
            const u16* vp = sKV + s*2048 + 256 + d;
            float c = a[0]*bf2f(vp[0]) + a[1]*bf2f(vp[512]) + a[2]*bf2f(vp[1024]) + a[3]*bf2f(vp[1536]);
            sQC[s*264 + d] = f2bf(c);
        }
    }
    __syncthreads();   // ctx visible; kv dead

    // ---- ao = ctx @ opw^T + opb via MFMA ----
    float* sAO = reinterpret_cast<float*>(sKV);   // f32 [16][264]
    {
        const int lane = t & 63, wid = t >> 6;
        const int la = lane & 15, hi = lane >> 4;
        f32x4 acc[4];
        #pragma unroll
        for (int n=0;n<4;n++){
            float4 b4 = *reinterpret_cast<const float4*>(opb + (wid<<6) + (n<<4) + (hi<<2));
            acc[n] = (f32x4){b4.x, b4.y, b4.z, b4.w};
        }
        #pragma unroll
        for (int ks=0; ks<8; ++ks){
            bf16x8 af = *reinterpret_cast<const bf16x8*>(sQC + la*264 + (ks<<5) + (hi<<3));
            #pragma unroll
            for (int n=0;n<4;n++){
                bf16x8 wf = *reinterpret_cast<const bf16x8*>(
                    opw + (size_t)((wid<<6) + (n<<4) + la)*256 + (ks<<5) + (hi<<3));
                acc[n] = __builtin_amdgcn_mfma_f32_16x16x32_bf16(wf, af, acc[n], 0, 0, 0);
            }
        }
        #pragma unroll
        for (int n=0;n<4;n++){
            float4 st = {acc[n][0], acc[n][1], acc[n][2], acc[n][3]};
            *reinterpret_cast<float4*>(sAO + la*264 + (wid<<6) + (n<<4) + (hi<<2)) = st;
        }
    }
    __syncthreads();

    // ---- entry = FiLM(LN(query + ao)) -> wcat row 0 ----
    {
        const int s = t >> 4, u = t & 15;
        u16* qrow = wcat + (size_t)(b0 + s)*1024;
        float xv[16], sum = 0.f, sq = 0.f;
        #pragma unroll
        for (int j=0;j<16;j++){
            const int d = u + (j << 4);
            float x = sAO[s*264 + d] + bf2f(qrow[d]);
            xv[j] = x; sum += x; sq += x*x;
        }
        #pragma unroll
        for (int o=1;o<16;o<<=1){ sum += __shfl_xor(sum, o); sq += __shfl_xor(sq, o); }
        float mu   = sum * (1.0f/256.0f);
        float var  = sq  * (1.0f/256.0f) - mu*mu;
        float rstd = rsqrtf(var + 1e-5f);
        const float r0 = regime[(b0+s)*4+0], r1 = regime[(b0+s)*4+1];
        const float r2 = regime[(b0+s)*4+2], r3 = regime[(b0+s)*4+3];
        #pragma unroll
        for (int j=0;j<16;j++){
            const int d = u + (j << 4);
            float gam = r0*sgw[d*4+0] + r1*sgw[d*4+1] + r2*sgw[d*4+2] + r3*sgw[d*4+3] + sgb[d];
            float bet = r0*sbw[d*4+0] + r1*sbw[d*4+1] + r2*sbw[d*4+2] + r3*sbw[d*4+3] + sbb[d];
            float e = ((xv[j]-mu)*rstd*g1[d] + b1[d])*(1.0f+gam) + bet;
            qrow[d] = f2bf(e);
        }
    }
}

// ---------------- fused = LN(t1) -> f32 out ----------------
__global__ __launch_bounds__(256) void ln2_kernel(
    const u16* __restrict__ t1, const float* __restrict__ g, const float* __restrict__ bt,
    float* __restrict__ out)
{
    const int b = blockIdx.x, t = threadIdx.x;
    float x0 = bf2f(t1[(size_t)b*512 + t]);
    float x1 = bf2f(t1[(size_t)b*512 + 256 + t]);
    float s = x0+x1, q = x0*x0 + x1*x1;
    #pragma unroll
    for (int o=32;o;o>>=1){ s += __shfl_xor(s,o); q += __shfl_xor(q,o); }
    __shared__ float rs[4], rq[4];
    if ((t&63)==0){ rs[t>>6]=s; rq[t>>6]=q; }
    __syncthreads();
    s = rs[0]+rs[1]+rs[2]+rs[3];
    q = rq[0]+rq[1]+rq[2]+rq[3];
    float mu  = s*(1.0f/512.0f);
    float var = q*(1.0f/512.0f) - mu*mu;
    float rstd = rsqrtf(var + 1e-5f);
    out[(size_t)b*512 + t]       = (x0-mu)*rstd*g[t]     + bt[t];
    out[(size_t)b*512 + 256 + t] = (x1-mu)*rstd*g[256+t] + bt[256+t];
}

extern "C" void kernel_launch(void* const* d_in, const int* in_sizes, int n_in,
                              void* d_out, int out_size, void* d_ws, size_t ws_size,
                              hipStream_t stream) {
    const float* w0   = (const float*)d_in[0];
    const float* w1   = (const float*)d_in[1];
    const float* w2   = (const float*)d_in[2];
    const float* w3   = (const float*)d_in[3];
    const float* regime = (const float*)d_in[4];
    const float* tfw  = (const float*)d_in[5];
    const float* in_proj_w = (const float*)d_in[6];
    const float* in_proj_b = (const float*)d_in[7];
    const float* out_proj_w = (const float*)d_in[8];
    const float* out_proj_b = (const float*)d_in[9];
    const float* ln1_g = (const float*)d_in[10];
    const float* ln1_b = (const float*)d_in[11];
    const float* sg_w = (const float*)d_in[12];
    const float* sg_b = (const float*)d_in[13];
    const float* sb_w = (const float*)d_in[14];
    const float* sb_b = (const float*)d_in[15];
    const float* f1_w = (const float*)d_in[16];
    const float* f1_b = (const float*)d_in[17];
    const float* f2_w = (const float*)d_in[18];
    const float* f2_b = (const float*)d_in[19];
    const float* ln2_g = (const float*)d_in[20];
    const float* ln2_b = (const float*)d_in[21];
    const float* a1_w = (const float*)d_in[22];
    const float* a1_b = (const float*)d_in[23];
    const float* a2_w = (const float*)d_in[24];
    const float* a2_b = (const float*)d_in[25];

    char* ws = (char*)d_ws;
    u16* wcat  = (u16*)(ws);
    u16* qbuf  = (u16*)(ws + 67108864ull);     // 64..80Mi
    u16* kvbuf = (u16*)(ws + 83886080ull);     // 80..208Mi
    u16* hbuf  = kvbuf;                        // 80..144Mi after attnop
    u16* t1buf = (u16*)(ws + 150994944ull);    // 144..176Mi
    u16* wb    = (u16*)(ws + 218103808ull);
    u16* ipw = wb;                // 196608 elems
    u16* opw = wb + 196608;       // 65536
    u16* f1w = wb + 262144;       // 1048576
    u16* f2w = wb + 1310720;      // 524288
    u16* a1w = wb + 1835008;      // 131072

    float* out_fused = (float*)d_out;
    float* out_align = (float*)d_out + (size_t)NB*512;

    // 1. prep + all weight conversions
    prepconv_kernel<<<10112, 256, 0, stream>>>(w0,w1,w2,w3,tfw,wcat,
        in_proj_w,ipw, out_proj_w,opw, f1_w,f1w, f2_w,f2w, a1_w,a1w);
    // 2. q = query @ wq^T + bq
    mgemm_kernel<0><<<dim3(256, 2), 256, 0, stream>>>(wcat, 1024, ipw, 256, in_proj_b, qbuf, 256, 256, nullptr, nullptr, nullptr);
    // 3. kv = weighted @ [wk;wv]^T + b
    gemm256p_kernel<0><<<dim3(512, 2), 512, 0, stream>>>(wcat, 256, ipw+65536, 256, in_proj_b+256, kvbuf, 512, 256);
    // 4. FUSED attention + out_proj + LN+FiLM -> wcat entry rows
    attnop_kernel<<<2048, 256, 0, stream>>>(qbuf, kvbuf, wcat, opw, out_proj_b,
        regime, sg_w, sg_b, sb_w, sb_b, ln1_g, ln1_b);
    // 5. h = gelu(cat @ f1^T + b) -> hbuf
    gemm256p_kernel<1><<<dim3(128, 4), 512, 0, stream>>>(wcat, 1024, f1w, 1024, f1_b, hbuf, 1024, 1024);
    // 6. alignment = sigmoid(gelu(cat @ a1^T + b) @ a2^T + b)  — moved here: wcat L2/L3-hot after f1
    mgemm_kernel<2><<<dim3(256, 1), 256, 0, stream>>>(wcat, 1024, a1w, 1024, a1_b, qbuf, 128, 1024, a2_w, a2_b, out_align);
    // 7. t1 = h @ f2^T + b
    gemm256p_kernel<0><<<dim3(128, 2), 512, 0, stream>>>(hbuf, 1024, f2w, 1024, f2_b, t1buf, 512, 1024);
    // 8. fused = LN(t1) -> out
    ln2_kernel<<<NB, 256, 0, stream>>>(t1buf, ln2_g, ln2_b, out_fused);
}